// Round 7
// baseline (484.476 us; speedup 1.0000x reference)
//
#include <hip/hip_runtime.h>

typedef __attribute__((ext_vector_type(8))) _Float16 half8;
typedef __attribute__((ext_vector_type(4))) _Float16 half4;
typedef __attribute__((ext_vector_type(4))) float    floatx4;

#define GLD16(g, l)                                                            \
  __builtin_amdgcn_global_load_lds(                                            \
      (const __attribute__((address_space(1))) void*)(g),                      \
      (__attribute__((address_space(3))) void*)(l), 16, 0, 0)

#define MFMA16(a, b, c) __builtin_amdgcn_mfma_f32_16x16x32_f16(a, b, c, 0, 0, 0)

__device__ __forceinline__ void cvt8(const float* __restrict__ in,
                                     _Float16* __restrict__ out, int i) {
  const float4* p = (const float4*)in + (size_t)i * 2;
  float4 a = p[0], b = p[1];
  half8 h;
  h[0] = (_Float16)a.x; h[1] = (_Float16)a.y; h[2] = (_Float16)a.z; h[3] = (_Float16)a.w;
  h[4] = (_Float16)b.x; h[5] = (_Float16)b.y; h[6] = (_Float16)b.z; h[7] = (_Float16)b.w;
  *(half8*)(out + (size_t)i * 8) = h;
}

// ---- prepA (fused): cvt emb (4096 blk) + cvt Wq (8192 blk) + prep_kv (8192) -
__global__ __launch_bounds__(256) void prepA(const float* __restrict__ emb,
                                             const float* __restrict__ Wq,
                                             const float* __restrict__ keys,
                                             const float* __restrict__ values,
                                             _Float16* __restrict__ embH,
                                             _Float16* __restrict__ WqH,
                                             _Float16* __restrict__ Kh,
                                             _Float16* __restrict__ Vt) {
  const int bid = blockIdx.x, t = threadIdx.x;
  if (bid < 4096) {
    cvt8(emb, embH, bid * 256 + t);
  } else if (bid < 12288) {
    cvt8(Wq, WqH, (bid - 4096) * 256 + t);
  } else {
    const int tid = (bid - 12288) * 256 + t;  // < 2M
    {
      int v = tid & 63, n = (tid >> 6) & 511, h = (tid >> 15) & 15, b = tid >> 19;
      Kh[tid] = (_Float16)keys[((size_t)(b * 512 + n)) * 1024 + v * 16 + h];
    }
    {
      int n = tid & 511, v = (tid >> 9) & 63, h = (tid >> 15) & 15, b = tid >> 19;
      Vt[tid] = (_Float16)values[((size_t)(b * 512 + n)) * 1024 + v * 16 + h];
    }
  }
}

// ---------------- GEMM_BT full-K, 128x128 tile, 4-wave, 4-phase, dbuf -------
// (unchanged from round 6 — 77.5 µs, MfmaUtil ~38%, at this geometry's LDS-
// throughput ceiling; see session notes. Kept as the stable known-good.)
template <int MODE>
__global__ __launch_bounds__(256, 2) void gemm_bt(const _Float16* __restrict__ A,
                                                  const _Float16* __restrict__ Bw,
                                                  const float* __restrict__ bias,
                                                  float* __restrict__ Cf,
                                                  _Float16* __restrict__ H0) {
  const int K = 4096;
  const int NT = 64;
  __shared__ _Float16 lA[2 * 8192];
  __shared__ _Float16 lB[2 * 8192];
  const int t = threadIdx.x, lane = t & 63, w = t >> 6;
  const int m0 = blockIdx.y * 128, n0 = blockIdx.x * 128;
  const int wm = (w >> 1) * 64, wn = (w & 1) * 64;
  const int fr = lane & 15, fq = lane >> 4;

  const int srow = t >> 3;                 // 0..31 (32 rows per GLD)
  const int sch = (t & 7) ^ (srow & 7);    // swizzled source chunk
  const _Float16* gA = A + (size_t)(m0 + srow) * K + sch * 8;
  const _Float16* gB = Bw + (size_t)(n0 + srow) * K + sch * 8;
  _Float16* dA = &lA[t * 8];
  _Float16* dB = &lB[t * 8];

#define STG(op, bf_, kt_, h_)                                                  \
  GLD16((op ? gB : gA) + (size_t)((h_)*32) * K + (kt_)*64,                     \
        (op ? dB : dA) + (bf_)*8192 + (h_)*2048)

  STG(0, 0, 0, 0); STG(0, 0, 0, 1); STG(0, 0, 0, 2); STG(0, 0, 0, 3);
  STG(1, 0, 0, 0); STG(1, 0, 0, 1); STG(1, 0, 0, 2); STG(1, 0, 0, 3);
  STG(0, 1, 1, 0); STG(0, 1, 1, 1); STG(0, 1, 1, 2); STG(0, 1, 1, 3);
  STG(1, 1, 1, 0); STG(1, 1, 1, 1); STG(1, 1, 1, 2); STG(1, 1, 1, 3);
  asm volatile("s_waitcnt vmcnt(8)" ::: "memory");
  __builtin_amdgcn_s_barrier();

  floatx4 acc[4][4];
#pragma unroll
  for (int i = 0; i < 4; i++)
#pragma unroll
    for (int j = 0; j < 4; j++) acc[i][j] = (floatx4)(0.f);

  const _Float16* cA = lA + (wm + fr) * 64;
  const _Float16* cB = lB + (wn + fr) * 64;
  const int xo0 = ((fq) ^ (fr & 7)) * 8;
  const int xo1 = ((4 + fq) ^ (fr & 7)) * 8;

#define QUAD(ibase, jbase)                                                     \
  do {                                                                         \
    __builtin_amdgcn_s_setprio(1);                                             \
    _Pragma("unroll") for (int i_ = 0; i_ < 2; i_++) {                         \
      _Pragma("unroll") for (int jj_ = 0; jj_ < 2; jj_++) {                    \
        acc[(ibase) + i_][(jbase) + jj_] = MFMA16(                             \
            af[(ibase) + i_][0], bf[(jbase) + jj_][0],                         \
            acc[(ibase) + i_][(jbase) + jj_]);                                 \
        acc[(ibase) + i_][(jbase) + jj_] = MFMA16(                             \
            af[(ibase) + i_][1], bf[(jbase) + jj_][1],                         \
            acc[(ibase) + i_][(jbase) + jj_]);                                 \
      }                                                                        \
    }                                                                          \
    __builtin_amdgcn_s_setprio(0);                                             \
  } while (0)

#define TILE(BUF, TT)                                                          \
  do {                                                                         \
    const int kt2 = ((TT) + 2 < NT) ? (TT) + 2 : NT - 1;                       \
    const int o = (BUF)*8192;                                                  \
    half8 af[4][2], bf[4][2];                                                  \
    _Pragma("unroll") for (int i = 0; i < 2; i++) {                            \
      af[i][0] = *(const half8*)(cA + o + i * 1024 + xo0);                     \
      af[i][1] = *(const half8*)(cA + o + i * 1024 + xo1);                     \
    }                                                                          \
    _Pragma("unroll") for (int j = 0; j < 2; j++) {                            \
      bf[j][0] = *(const half8*)(cB + o + j * 1024 + xo0);                     \
      bf[j][1] = *(const half8*)(cB + o + j * 1024 + xo1);                     \
    }                                                                          \
    __builtin_amdgcn_s_barrier();                                              \
    asm volatile("s_waitcnt lgkmcnt(0)" ::: "memory");                         \
    QUAD(0, 0);                                                                \
    __builtin_amdgcn_s_barrier();                                              \
    STG(0, (BUF), kt2, 0); STG(0, (BUF), kt2, 2);                              \
    STG(1, (BUF), kt2, 0); STG(1, (BUF), kt2, 2);                              \
    _Pragma("unroll") for (int i = 2; i < 4; i++) {                            \
      af[i][0] = *(const half8*)(cA + o + i * 1024 + xo0);                     \
      af[i][1] = *(const half8*)(cA + o + i * 1024 + xo1);                     \
    }                                                                          \
    __builtin_amdgcn_s_barrier();                                              \
    asm volatile("s_waitcnt lgkmcnt(0)" ::: "memory");                         \
    QUAD(2, 0);                                                                \
    __builtin_amdgcn_s_barrier();                                              \
    STG(0, (BUF), kt2, 1); STG(0, (BUF), kt2, 3);                              \
    _Pragma("unroll") for (int j = 2; j < 4; j++) {                            \
      bf[j][0] = *(const half8*)(cB + o + j * 1024 + xo0);                     \
      bf[j][1] = *(const half8*)(cB + o + j * 1024 + xo1);                     \
    }                                                                          \
    __builtin_amdgcn_s_barrier();                                              \
    asm volatile("s_waitcnt lgkmcnt(0)" ::: "memory");                         \
    QUAD(0, 2);                                                                \
    __builtin_amdgcn_s_barrier();                                              \
    STG(1, (BUF), kt2, 1); STG(1, (BUF), kt2, 3);                              \
    __builtin_amdgcn_s_barrier();                                              \
    QUAD(2, 2);                                                                \
    asm volatile("s_waitcnt vmcnt(8)" ::: "memory");                           \
    __builtin_amdgcn_s_barrier();                                              \
  } while (0)

  for (int tt = 0; tt < NT; tt += 2) {
    TILE(0, tt);
    TILE(1, tt + 1);
  }

#pragma unroll
  for (int i = 0; i < 4; i++)
#pragma unroll
    for (int j = 0; j < 4; j++) {
      const int col = n0 + wn + j * 16 + fr;
      const int rbase = m0 + wm + i * 16 + fq * 4;
      if (MODE == 0) {
        const float bv = bias[col];
#pragma unroll
        for (int r = 0; r < 4; r++)
          Cf[(size_t)(rbase + r) * 4096 + col] = acc[i][j][r] + bv;
      } else {
#pragma unroll
        for (int r = 0; r < 4; r++)
          H0[(size_t)(rbase + r) * 4096 + col] = (_Float16)acc[i][j][r];
      }
    }
#undef TILE
#undef QUAD
#undef STG
}

// ---- prepB (fused): cvt Wre (8192 blk) + combine1 (2048 blk) ----------------
__global__ __launch_bounds__(256) void prepB(const float* __restrict__ Wre,
                                             _Float16* __restrict__ WreH,
                                             const _Float16* __restrict__ p0,
                                             const float* __restrict__ bq,
                                             _Float16* __restrict__ q) {
  const int bid = blockIdx.x, t = threadIdx.x;
  if (bid < 8192) {
    cvt8(Wre, WreH, bid * 256 + t);
    return;
  }
  __shared__ _Float16 T[4][16][80];  // row stride 160B: 16B-aligned, bank-rotating
  const int L = t & 63, w = t >> 6;
  const int m = bid - 8192, d = w;
  const int b = m >> 9, s = m & 511;
  const size_t src = (size_t)m * 4096 + d * 1024 + L * 16;
  half8 a0 = *(const half8*)(p0 + src);
  half8 a1 = *(const half8*)(p0 + src + 8);
  const float4* bqv = (const float4*)(bq + d * 1024 + L * 16);
  float bias[16];
#pragma unroll
  for (int c = 0; c < 4; c++) {
    float4 f = bqv[c];
    bias[c * 4 + 0] = f.x; bias[c * 4 + 1] = f.y;
    bias[c * 4 + 2] = f.z; bias[c * 4 + 3] = f.w;
  }
#pragma unroll
  for (int h = 0; h < 8; h++) {
    T[w][h][L] = (_Float16)(((float)a0[h] + bias[h]) * 0.125f);
    T[w][h + 8][L] = (_Float16)(((float)a1[h] + bias[h + 8]) * 0.125f);
  }
  const int h2 = L >> 2, c2 = L & 3;
  _Float16* dst = q + (((size_t)(b * 16 + h2) * 2048) + s * 4 + d) * 64 + c2 * 8;
  *(half8*)dst = *(const half8*)&T[w][h2][c2 * 8];
  *(half8*)(dst + 32) = *(const half8*)&T[w][h2][32 + c2 * 8];
}

// ---------------- MFMA flash attention v2 -----------------------------------
// grid (32 q-tiles, 64 bh), 256 thr = 4 waves; each wave owns 16 q-rows.
// Occupancy-focused restructure of the verified v1 algebra (i-dim dropped):
//   - per-wave state halved: sc[8] (32 VGPR), oacc[4] (16), qf[2] (8)
//   - V prefetch 2-deep by kn parity (vrA/vrB, 16+16 VGPR) instead of the
//     full vr[4][4] hoist (64 VGPR) — latency still hidden, peak regs ~90
//   - Pbuf per-wave [16][136] (17.4 KB/block)
// Target ~5 waves/SIMD (vs ~2 in v1) + 2048 blocks (8/CU grain) to convert
// the 85%-idle latency-chain profile into overlapped waves.
__global__ __launch_bounds__(256) void attn_mfma(const _Float16* __restrict__ Q,
                                                 const _Float16* __restrict__ Kh,
                                                 const _Float16* __restrict__ Vt,
                                                 float* __restrict__ Out) {
  __shared__ _Float16 Pbuf[4][16][136];
  const int t = threadIdx.x, lane = t & 63, w = t >> 6;
  const int fr = lane & 15, fq = lane >> 4;
  const int bh = blockIdx.y, qt = blockIdx.x;  // qt 0..31
  const int b = bh >> 4, h = bh & 15;

  const _Float16* Qb = Q + ((size_t)bh * 2048 + qt * 64 + w * 16) * 64;
  const _Float16* Kb = Kh + (size_t)bh * 512 * 64;
  const _Float16* Vb = Vt + (size_t)bh * 64 * 512;

  half8 qf[2];
#pragma unroll
  for (int ks = 0; ks < 2; ks++)
    qf[ks] = *(const half8*)(Qb + fr * 64 + ks * 32 + fq * 8);

  floatx4 oacc[4];
  float l_acc[4];
#pragma unroll
  for (int j = 0; j < 4; j++) {
    oacc[j] = (floatx4)(0.f);
    l_acc[j] = 0.f;
  }

  for (int c0 = 0; c0 < 512; c0 += 128) {
    floatx4 sc[8];
#pragma unroll
    for (int j = 0; j < 8; j++) sc[j] = (floatx4)(0.f);
#pragma unroll
    for (int j = 0; j < 8; j++) {
      const _Float16* kr = Kb + (size_t)(c0 + j * 16 + fr) * 64 + fq * 8;
      half8 k0 = *(const half8*)kr;
      half8 k1 = *(const half8*)(kr + 32);
      sc[j] = MFMA16(qf[0], k0, sc[j]);
      sc[j] = MFMA16(qf[1], k1, sc[j]);
    }
    // prefetch V kn=0 before the exp section (latency drains under VALU)
    half8 vrA[4], vrB[4];
#pragma unroll
    for (int jv = 0; jv < 4; jv++)
      vrA[jv] = *(const half8*)(Vb + (size_t)(jv * 16 + fr) * 512 + c0 + fq * 8);
#pragma unroll
    for (int j = 0; j < 8; j++)
#pragma unroll
      for (int r = 0; r < 4; r++) {
        float p = __expf(sc[j][r]);
        l_acc[r] += p;
        Pbuf[w][fq * 4 + r][j * 16 + fr] = (_Float16)p;
      }
#pragma unroll
    for (int kn = 0; kn < 4; kn++) {
      // issue next kn's V loads before consuming current (2-deep pipeline)
      if (kn == 0 || kn == 2) {
#pragma unroll
        for (int jv = 0; jv < 4; jv++)
          vrB[jv] = *(const half8*)(Vb + (size_t)(jv * 16 + fr) * 512 + c0 +
                                    (kn + 1) * 32 + fq * 8);
      } else if (kn == 1) {
#pragma unroll
        for (int jv = 0; jv < 4; jv++)
          vrA[jv] = *(const half8*)(Vb + (size_t)(jv * 16 + fr) * 512 + c0 +
                                    (kn + 1) * 32 + fq * 8);
      }
      half8 pa = *(const half8*)&Pbuf[w][fr][kn * 32 + fq * 8];
#pragma unroll
      for (int jv = 0; jv < 4; jv++) {
        half8 vb = (kn & 1) ? vrB[jv] : vrA[jv];
        oacc[jv] = MFMA16(pa, vb, oacc[jv]);
      }
    }
  }

#pragma unroll
  for (int r = 0; r < 4; r++)
#pragma unroll
    for (int m = 8; m; m >>= 1)
      l_acc[r] += __shfl_xor(l_acc[r], m, 16);

#pragma unroll
  for (int r = 0; r < 4; r++) {
    const float inv = 1.f / l_acc[r];
    const int m2 = qt * 64 + w * 16 + fq * 4 + r;
    float* orow = Out + ((size_t)(b * 512 + (m2 >> 2))) * 4096 + h * 256 +
                  (m2 & 3) * 64 + fr;
#pragma unroll
    for (int jv = 0; jv < 4; jv++) orow[jv * 16] = oacc[jv][r] * inv;
  }
}

// ---------------- LayerNorm over 4096, output f16 ---------------------------
__global__ __launch_bounds__(256) void ln_kernel(const float* __restrict__ X,
                                                 const float* __restrict__ g,
                                                 const float* __restrict__ bb,
                                                 _Float16* __restrict__ Y) {
  const int row = blockIdx.x;
  const int t = threadIdx.x;
  const float* x = X + (size_t)row * 4096;
  float4 vals[4];
  float sum = 0.f, sq = 0.f;
#pragma unroll
  for (int c = 0; c < 4; c++) {
    vals[c] = *(const float4*)&x[c * 1024 + t * 4];
    sum += vals[c].x + vals[c].y + vals[c].z + vals[c].w;
    sq += vals[c].x * vals[c].x + vals[c].y * vals[c].y + vals[c].z * vals[c].z +
          vals[c].w * vals[c].w;
  }
#pragma unroll
  for (int off = 32; off > 0; off >>= 1) {
    sum += __shfl_down(sum, off, 64);
    sq += __shfl_down(sq, off, 64);
  }
  __shared__ float red[8];
  const int w = t >> 6;
  if ((t & 63) == 0) {
    red[w] = sum;
    red[4 + w] = sq;
  }
  __syncthreads();
  sum = red[0] + red[1] + red[2] + red[3];
  sq = red[4] + red[5] + red[6] + red[7];
  const float mu = sum * (1.f / 4096.f);
  float var = sq * (1.f / 4096.f) - mu * mu;
  var = fmaxf(var, 0.f);
  const float rstd = rsqrtf(var + 1e-12f);
#pragma unroll
  for (int c = 0; c < 4; c++) {
    const int j = c * 1024 + t * 4;
    float4 gg = *(const float4*)&g[j];
    float4 bv = *(const float4*)&bb[j];
    half4 y;
    y[0] = (_Float16)((vals[c].x - mu) * rstd * gg.x + bv.x);
    y[1] = (_Float16)((vals[c].y - mu) * rstd * gg.y + bv.y);
    y[2] = (_Float16)((vals[c].z - mu) * rstd * gg.z + bv.z);
    y[3] = (_Float16)((vals[c].w - mu) * rstd * gg.w + bv.w);
    *(half4*)&Y[(size_t)row * 4096 + j] = y;
  }
}

// ---------------- launcher --------------------------------------------------
extern "C" void kernel_launch(void* const* d_in, const int* in_sizes, int n_in,
                              void* d_out, int out_size, void* d_ws,
                              size_t ws_size, hipStream_t stream) {
  const float* emb = (const float*)d_in[0];
  const float* keys = (const float*)d_in[1];
  const float* values = (const float*)d_in[2];
  const float* Wq = (const float*)d_in[3];
  const float* bq = (const float*)d_in[4];
  const float* Wre = (const float*)d_in[5];
  const float* bre = (const float*)d_in[6];
  const float* ln_g = (const float*)d_in[7];
  const float* ln_b = (const float*)d_in[8];
  float* out = (float*)d_out;

  char* ws = (char*)d_ws;
  // ws timeline (64 MiB) + d_out (32 MiB) as scratch. No split-K partials.
  //  1. prepA: embH [0,16); WqH [16,48); Kh [48,52); Vt [52,56)
  //  2. gemm1<1>: -> H f16 = d_out[0,16M)
  //  3. prepB: WreH [16,48) (WqH dead); combine1(H) -> qattn [0,16) (embH dead)
  //  4. attn(qattn,Kh,Vt) -> d_out f32            (H dead)
  //  5. ln -> lnH [48,64)                         (Kh/Vt dead)
  //  6. gemm2<0>: f32 + bre -> d_out              (final; no combine)
  _Float16* embH = (_Float16*)(ws);
  _Float16* WqH = (_Float16*)(ws + ((size_t)16 << 20));
  _Float16* Kh = (_Float16*)(ws + ((size_t)48 << 20));
  _Float16* Vt = (_Float16*)(ws + ((size_t)52 << 20));
  _Float16* P0q = (_Float16*)d_out;
  _Float16* WreH = WqH;
  _Float16* qattn = (_Float16*)(ws);
  _Float16* lnH = (_Float16*)(ws + ((size_t)48 << 20));

  prepA<<<20480, 256, 0, stream>>>(emb, Wq, keys, values, embH, WqH, Kh, Vt);
  gemm_bt<1><<<dim3(32, 16), 256, 0, stream>>>(embH, WqH, nullptr, nullptr, P0q);
  prepB<<<10240, 256, 0, stream>>>(Wre, WreH, P0q, bq, qattn);
  attn_mfma<<<dim3(32, 64), 256, 0, stream>>>(qattn, Kh, Vt, out);
  ln_kernel<<<2048, 256, 0, stream>>>(out, ln_g, ln_b, lnH);
  gemm_bt<0><<<dim3(32, 16), 256, 0, stream>>>(lnH, WreH, bre, out, nullptr);
}

// Round 9
// 428.061 us; speedup vs baseline: 1.1318x; 1.1318x over previous
//
#include <hip/hip_runtime.h>

typedef __attribute__((ext_vector_type(8))) _Float16 half8;
typedef __attribute__((ext_vector_type(4))) _Float16 half4;
typedef __attribute__((ext_vector_type(4))) float    floatx4;

#define GLD16(g, l)                                                            \
  __builtin_amdgcn_global_load_lds(                                            \
      (const __attribute__((address_space(1))) void*)(g),                      \
      (__attribute__((address_space(3))) void*)(l), 16, 0, 0)

#define MFMA16(a, b, c) __builtin_amdgcn_mfma_f32_16x16x32_f16(a, b, c, 0, 0, 0)

__device__ __forceinline__ void cvt8(const float* __restrict__ in,
                                     _Float16* __restrict__ out, int i) {
  const float4* p = (const float4*)in + (size_t)i * 2;
  float4 a = p[0], b = p[1];
  half8 h;
  h[0] = (_Float16)a.x; h[1] = (_Float16)a.y; h[2] = (_Float16)a.z; h[3] = (_Float16)a.w;
  h[4] = (_Float16)b.x; h[5] = (_Float16)b.y; h[6] = (_Float16)b.z; h[7] = (_Float16)b.w;
  *(half8*)(out + (size_t)i * 8) = h;
}

// ---- prepA (fused): cvt emb (4096 blk) + cvt Wq (8192 blk) + prep_kv (8192) -
__global__ __launch_bounds__(256) void prepA(const float* __restrict__ emb,
                                             const float* __restrict__ Wq,
                                             const float* __restrict__ keys,
                                             const float* __restrict__ values,
                                             _Float16* __restrict__ embH,
                                             _Float16* __restrict__ WqH,
                                             _Float16* __restrict__ Kh,
                                             _Float16* __restrict__ Vt) {
  const int bid = blockIdx.x, t = threadIdx.x;
  if (bid < 4096) {
    cvt8(emb, embH, bid * 256 + t);
  } else if (bid < 12288) {
    cvt8(Wq, WqH, (bid - 4096) * 256 + t);
  } else {
    const int tid = (bid - 12288) * 256 + t;  // < 2M
    {
      int v = tid & 63, n = (tid >> 6) & 511, h = (tid >> 15) & 15, b = tid >> 19;
      Kh[tid] = (_Float16)keys[((size_t)(b * 512 + n)) * 1024 + v * 16 + h];
    }
    {
      int n = tid & 511, v = (tid >> 9) & 63, h = (tid >> 15) & 15, b = tid >> 19;
      Vt[tid] = (_Float16)values[((size_t)(b * 512 + n)) * 1024 + v * 16 + h];
    }
  }
}

// ---------------- GEMM_BT full-K, 128x128 tile, 4-wave, 4-phase, dbuf -------
// (unchanged from round 6 — 77.5 µs, MfmaUtil ~38%, at this geometry's LDS-
// throughput ceiling; see session notes. Kept as the stable known-good.)
template <int MODE>
__global__ __launch_bounds__(256, 2) void gemm_bt(const _Float16* __restrict__ A,
                                                  const _Float16* __restrict__ Bw,
                                                  const float* __restrict__ bias,
                                                  float* __restrict__ Cf,
                                                  _Float16* __restrict__ H0) {
  const int K = 4096;
  const int NT = 64;
  __shared__ _Float16 lA[2 * 8192];
  __shared__ _Float16 lB[2 * 8192];
  const int t = threadIdx.x, lane = t & 63, w = t >> 6;
  const int m0 = blockIdx.y * 128, n0 = blockIdx.x * 128;
  const int wm = (w >> 1) * 64, wn = (w & 1) * 64;
  const int fr = lane & 15, fq = lane >> 4;

  const int srow = t >> 3;                 // 0..31 (32 rows per GLD)
  const int sch = (t & 7) ^ (srow & 7);    // swizzled source chunk
  const _Float16* gA = A + (size_t)(m0 + srow) * K + sch * 8;
  const _Float16* gB = Bw + (size_t)(n0 + srow) * K + sch * 8;
  _Float16* dA = &lA[t * 8];
  _Float16* dB = &lB[t * 8];

#define STG(op, bf_, kt_, h_)                                                  \
  GLD16((op ? gB : gA) + (size_t)((h_)*32) * K + (kt_)*64,                     \
        (op ? dB : dA) + (bf_)*8192 + (h_)*2048)

  STG(0, 0, 0, 0); STG(0, 0, 0, 1); STG(0, 0, 0, 2); STG(0, 0, 0, 3);
  STG(1, 0, 0, 0); STG(1, 0, 0, 1); STG(1, 0, 0, 2); STG(1, 0, 0, 3);
  STG(0, 1, 1, 0); STG(0, 1, 1, 1); STG(0, 1, 1, 2); STG(0, 1, 1, 3);
  STG(1, 1, 1, 0); STG(1, 1, 1, 1); STG(1, 1, 1, 2); STG(1, 1, 1, 3);
  asm volatile("s_waitcnt vmcnt(8)" ::: "memory");
  __builtin_amdgcn_s_barrier();

  floatx4 acc[4][4];
#pragma unroll
  for (int i = 0; i < 4; i++)
#pragma unroll
    for (int j = 0; j < 4; j++) acc[i][j] = (floatx4)(0.f);

  const _Float16* cA = lA + (wm + fr) * 64;
  const _Float16* cB = lB + (wn + fr) * 64;
  const int xo0 = ((fq) ^ (fr & 7)) * 8;
  const int xo1 = ((4 + fq) ^ (fr & 7)) * 8;

#define QUAD(ibase, jbase)                                                     \
  do {                                                                         \
    __builtin_amdgcn_s_setprio(1);                                             \
    _Pragma("unroll") for (int i_ = 0; i_ < 2; i_++) {                         \
      _Pragma("unroll") for (int jj_ = 0; jj_ < 2; jj_++) {                    \
        acc[(ibase) + i_][(jbase) + jj_] = MFMA16(                             \
            af[(ibase) + i_][0], bf[(jbase) + jj_][0],                         \
            acc[(ibase) + i_][(jbase) + jj_]);                                 \
        acc[(ibase) + i_][(jbase) + jj_] = MFMA16(                             \
            af[(ibase) + i_][1], bf[(jbase) + jj_][1],                         \
            acc[(ibase) + i_][(jbase) + jj_]);                                 \
      }                                                                        \
    }                                                                          \
    __builtin_amdgcn_s_setprio(0);                                             \
  } while (0)

#define TILE(BUF, TT)                                                          \
  do {                                                                         \
    const int kt2 = ((TT) + 2 < NT) ? (TT) + 2 : NT - 1;                       \
    const int o = (BUF)*8192;                                                  \
    half8 af[4][2], bf[4][2];                                                  \
    _Pragma("unroll") for (int i = 0; i < 2; i++) {                            \
      af[i][0] = *(const half8*)(cA + o + i * 1024 + xo0);                     \
      af[i][1] = *(const half8*)(cA + o + i * 1024 + xo1);                     \
    }                                                                          \
    _Pragma("unroll") for (int j = 0; j < 2; j++) {                            \
      bf[j][0] = *(const half8*)(cB + o + j * 1024 + xo0);                     \
      bf[j][1] = *(const half8*)(cB + o + j * 1024 + xo1);                     \
    }                                                                          \
    __builtin_amdgcn_s_barrier();                                              \
    asm volatile("s_waitcnt lgkmcnt(0)" ::: "memory");                         \
    QUAD(0, 0);                                                                \
    __builtin_amdgcn_s_barrier();                                              \
    STG(0, (BUF), kt2, 0); STG(0, (BUF), kt2, 2);                              \
    STG(1, (BUF), kt2, 0); STG(1, (BUF), kt2, 2);                              \
    _Pragma("unroll") for (int i = 2; i < 4; i++) {                            \
      af[i][0] = *(const half8*)(cA + o + i * 1024 + xo0);                     \
      af[i][1] = *(const half8*)(cA + o + i * 1024 + xo1);                     \
    }                                                                          \
    __builtin_amdgcn_s_barrier();                                              \
    asm volatile("s_waitcnt lgkmcnt(0)" ::: "memory");                         \
    QUAD(2, 0);                                                                \
    __builtin_amdgcn_s_barrier();                                              \
    STG(0, (BUF), kt2, 1); STG(0, (BUF), kt2, 3);                              \
    _Pragma("unroll") for (int j = 2; j < 4; j++) {                            \
      bf[j][0] = *(const half8*)(cB + o + j * 1024 + xo0);                     \
      bf[j][1] = *(const half8*)(cB + o + j * 1024 + xo1);                     \
    }                                                                          \
    __builtin_amdgcn_s_barrier();                                              \
    asm volatile("s_waitcnt lgkmcnt(0)" ::: "memory");                         \
    QUAD(0, 2);                                                                \
    __builtin_amdgcn_s_barrier();                                              \
    STG(1, (BUF), kt2, 1); STG(1, (BUF), kt2, 3);                              \
    __builtin_amdgcn_s_barrier();                                              \
    QUAD(2, 2);                                                                \
    asm volatile("s_waitcnt vmcnt(8)" ::: "memory");                           \
    __builtin_amdgcn_s_barrier();                                              \
  } while (0)

  for (int tt = 0; tt < NT; tt += 2) {
    TILE(0, tt);
    TILE(1, tt + 1);
  }

#pragma unroll
  for (int i = 0; i < 4; i++)
#pragma unroll
    for (int j = 0; j < 4; j++) {
      const int col = n0 + wn + j * 16 + fr;
      const int rbase = m0 + wm + i * 16 + fq * 4;
      if (MODE == 0) {
        const float bv = bias[col];
#pragma unroll
        for (int r = 0; r < 4; r++)
          Cf[(size_t)(rbase + r) * 4096 + col] = acc[i][j][r] + bv;
      } else {
#pragma unroll
        for (int r = 0; r < 4; r++)
          H0[(size_t)(rbase + r) * 4096 + col] = (_Float16)acc[i][j][r];
      }
    }
#undef TILE
#undef QUAD
#undef STG
}

// ---- prepB (fused): cvt Wre (8192 blk) + combine1 (2048 blk) ----------------
__global__ __launch_bounds__(256) void prepB(const float* __restrict__ Wre,
                                             _Float16* __restrict__ WreH,
                                             const _Float16* __restrict__ p0,
                                             const float* __restrict__ bq,
                                             _Float16* __restrict__ q) {
  const int bid = blockIdx.x, t = threadIdx.x;
  if (bid < 8192) {
    cvt8(Wre, WreH, bid * 256 + t);
    return;
  }
  __shared__ _Float16 T[4][16][80];  // row stride 160B: 16B-aligned, bank-rotating
  const int L = t & 63, w = t >> 6;
  const int m = bid - 8192, d = w;
  const int b = m >> 9, s = m & 511;
  const size_t src = (size_t)m * 4096 + d * 1024 + L * 16;
  half8 a0 = *(const half8*)(p0 + src);
  half8 a1 = *(const half8*)(p0 + src + 8);
  const float4* bqv = (const float4*)(bq + d * 1024 + L * 16);
  float bias[16];
#pragma unroll
  for (int c = 0; c < 4; c++) {
    float4 f = bqv[c];
    bias[c * 4 + 0] = f.x; bias[c * 4 + 1] = f.y;
    bias[c * 4 + 2] = f.z; bias[c * 4 + 3] = f.w;
  }
#pragma unroll
  for (int h = 0; h < 8; h++) {
    T[w][h][L] = (_Float16)(((float)a0[h] + bias[h]) * 0.125f);
    T[w][h + 8][L] = (_Float16)(((float)a1[h] + bias[h + 8]) * 0.125f);
  }
  const int h2 = L >> 2, c2 = L & 3;
  _Float16* dst = q + (((size_t)(b * 16 + h2) * 2048) + s * 4 + d) * 64 + c2 * 8;
  *(half8*)dst = *(const half8*)&T[w][h2][c2 * 8];
  *(half8*)(dst + 32) = *(const half8*)&T[w][h2][32 + c2 * 8];
}

// ---------------- MFMA flash attention (v1 + exp/PV interleave) -------------
// grid (16 q-tiles, 64 bh), 256 threads = 4 waves. Q-tile 128 rows, 32/wave.
// Round-6 v1 structure (full vr[4][4] hoist) with ONE change: the exp/softmax
// VALU work is sliced by PV step kn — PV step kn only consumes P-columns
// [kn*32, kn*32+32) = exp of j ∈ {2kn, 2kn+1} — so each pa read waits on 1/4
// of the exp work, and PV-kn's MFMAs (matrix pipe) execute under exp-(kn+1)'s
// VALU (in-order issue, independent ops, separate pipes; no barriers in this
// kernel). setprio(1) wraps the PV MFMA cluster (T5: waves sit at different
// phases here, so priority arbitration has something to do).
__global__ __launch_bounds__(256) void attn_mfma(const _Float16* __restrict__ Q,
                                                 const _Float16* __restrict__ Kh,
                                                 const _Float16* __restrict__ Vt,
                                                 float* __restrict__ Out) {
  __shared__ _Float16 Pbuf[4][32][136];
  const int t = threadIdx.x, lane = t & 63, w = t >> 6;
  const int fr = lane & 15, fq = lane >> 4;
  const int bh = blockIdx.y, qt = blockIdx.x;
  const int b = bh >> 4, h = bh & 15;

  const _Float16* Qb = Q + ((size_t)bh * 2048 + qt * 128 + w * 32) * 64;
  const _Float16* Kb = Kh + (size_t)bh * 512 * 64;
  const _Float16* Vb = Vt + (size_t)bh * 64 * 512;

  half8 qf[2][2];
#pragma unroll
  for (int i = 0; i < 2; i++)
#pragma unroll
    for (int ks = 0; ks < 2; ks++)
      qf[i][ks] = *(const half8*)(Qb + (i * 16 + fr) * 64 + ks * 32 + fq * 8);

  floatx4 oacc[2][4];
  float l_acc[2][4];
#pragma unroll
  for (int i = 0; i < 2; i++)
#pragma unroll
    for (int j = 0; j < 4; j++) {
      oacc[i][j] = (floatx4)(0.f);
      l_acc[i][j] = 0.f;
    }

  for (int c0 = 0; c0 < 512; c0 += 128) {
    floatx4 sc[2][8];
#pragma unroll
    for (int i = 0; i < 2; i++)
#pragma unroll
      for (int j = 0; j < 8; j++) sc[i][j] = (floatx4)(0.f);
#pragma unroll
    for (int j = 0; j < 8; j++) {
      const _Float16* kr = Kb + (size_t)(c0 + j * 16 + fr) * 64 + fq * 8;
      half8 k0 = *(const half8*)kr;
      half8 k1 = *(const half8*)(kr + 32);
#pragma unroll
      for (int i = 0; i < 2; i++) {
        sc[i][j] = MFMA16(qf[i][0], k0, sc[i][j]);
        sc[i][j] = MFMA16(qf[i][1], k1, sc[i][j]);
      }
    }
    // ---- hoisted V loads: issue all 16 before the softmax/PV section ----
    half8 vr[4][4];
#pragma unroll
    for (int kn = 0; kn < 4; kn++)
#pragma unroll
      for (int jv = 0; jv < 4; jv++)
        vr[kn][jv] =
            *(const half8*)(Vb + (size_t)(jv * 16 + fr) * 512 + c0 + kn * 32 + fq * 8);
    // ---- interleaved: exp slice kn (j=2kn,2kn+1) then PV step kn ----
#pragma unroll
    for (int kn = 0; kn < 4; kn++) {
#pragma unroll
      for (int jj = 0; jj < 2; jj++) {
        const int j = kn * 2 + jj;
#pragma unroll
        for (int i = 0; i < 2; i++)
#pragma unroll
          for (int r = 0; r < 4; r++) {
            float p = __expf(sc[i][j][r]);
            l_acc[i][r] += p;
            Pbuf[w][i * 16 + fq * 4 + r][j * 16 + fr] = (_Float16)p;
          }
      }
      half8 pa[2];
#pragma unroll
      for (int i = 0; i < 2; i++)
        pa[i] = *(const half8*)&Pbuf[w][i * 16 + fr][kn * 32 + fq * 8];
      __builtin_amdgcn_s_setprio(1);
#pragma unroll
      for (int jv = 0; jv < 4; jv++) {
#pragma unroll
        for (int i = 0; i < 2; i++)
          oacc[i][jv] = MFMA16(pa[i], vr[kn][jv], oacc[i][jv]);
      }
      __builtin_amdgcn_s_setprio(0);
    }
  }

#pragma unroll
  for (int i = 0; i < 2; i++)
#pragma unroll
    for (int r = 0; r < 4; r++) {
#pragma unroll
      for (int m = 8; m; m >>= 1)
        l_acc[i][r] += __shfl_xor(l_acc[i][r], m, 16);
    }
#pragma unroll
  for (int i = 0; i < 2; i++) {
#pragma unroll
    for (int r = 0; r < 4; r++) {
      const float inv = 1.f / l_acc[i][r];
      const int m2 = qt * 128 + w * 32 + i * 16 + fq * 4 + r;
      float* orow = Out + ((size_t)(b * 512 + (m2 >> 2))) * 4096 + h * 256 + (m2 & 3) * 64 + fr;
#pragma unroll
      for (int jv = 0; jv < 4; jv++) orow[jv * 16] = oacc[i][jv][r] * inv;
    }
  }
}

// ---------------- LayerNorm over 4096, output f16 ---------------------------
__global__ __launch_bounds__(256) void ln_kernel(const float* __restrict__ X,
                                                 const float* __restrict__ g,
                                                 const float* __restrict__ bb,
                                                 _Float16* __restrict__ Y) {
  const int row = blockIdx.x;
  const int t = threadIdx.x;
  const float* x = X + (size_t)row * 4096;
  float4 vals[4];
  float sum = 0.f, sq = 0.f;
#pragma unroll
  for (int c = 0; c < 4; c++) {
    vals[c] = *(const float4*)&x[c * 1024 + t * 4];
    sum += vals[c].x + vals[c].y + vals[c].z + vals[c].w;
    sq += vals[c].x * vals[c].x + vals[c].y * vals[c].y + vals[c].z * vals[c].z +
          vals[c].w * vals[c].w;
  }
#pragma unroll
  for (int off = 32; off > 0; off >>= 1) {
    sum += __shfl_down(sum, off, 64);
    sq += __shfl_down(sq, off, 64);
  }
  __shared__ float red[8];
  const int w = t >> 6;
  if ((t & 63) == 0) {
    red[w] = sum;
    red[4 + w] = sq;
  }
  __syncthreads();
  sum = red[0] + red[1] + red[2] + red[3];
  sq = red[4] + red[5] + red[6] + red[7];
  const float mu = sum * (1.f / 4096.f);
  float var = sq * (1.f / 4096.f) - mu * mu;
  var = fmaxf(var, 0.f);
  const float rstd = rsqrtf(var + 1e-12f);
#pragma unroll
  for (int c = 0; c < 4; c++) {
    const int j = c * 1024 + t * 4;
    float4 gg = *(const float4*)&g[j];
    float4 bv = *(const float4*)&bb[j];
    half4 y;
    y[0] = (_Float16)((vals[c].x - mu) * rstd * gg.x + bv.x);
    y[1] = (_Float16)((vals[c].y - mu) * rstd * gg.y + bv.y);
    y[2] = (_Float16)((vals[c].z - mu) * rstd * gg.z + bv.z);
    y[3] = (_Float16)((vals[c].w - mu) * rstd * gg.w + bv.w);
    *(half4*)&Y[(size_t)row * 4096 + j] = y;
  }
}

// ---------------- launcher --------------------------------------------------
extern "C" void kernel_launch(void* const* d_in, const int* in_sizes, int n_in,
                              void* d_out, int out_size, void* d_ws,
                              size_t ws_size, hipStream_t stream) {
  const float* emb = (const float*)d_in[0];
  const float* keys = (const float*)d_in[1];
  const float* values = (const float*)d_in[2];
  const float* Wq = (const float*)d_in[3];
  const float* bq = (const float*)d_in[4];
  const float* Wre = (const float*)d_in[5];
  const float* bre = (const float*)d_in[6];
  const float* ln_g = (const float*)d_in[7];
  const float* ln_b = (const float*)d_in[8];
  float* out = (float*)d_out;

  char* ws = (char*)d_ws;
  // ws timeline (64 MiB) + d_out (32 MiB) as scratch. No split-K partials.
  //  1. prepA: embH [0,16); WqH [16,48); Kh [48,52); Vt [52,56)
  //  2. gemm1<1>: -> H f16 = d_out[0,16M)
  //  3. prepB: WreH [16,48) (WqH dead); combine1(H) -> qattn [0,16) (embH dead)
  //  4. attn(qattn,Kh,Vt) -> d_out f32            (H dead)
  //  5. ln -> lnH [48,64)                         (Kh/Vt dead)
  //  6. gemm2<0>: f32 + bre -> d_out              (final; no combine)
  _Float16* embH = (_Float16*)(ws);
  _Float16* WqH = (_Float16*)(ws + ((size_t)16 << 20));
  _Float16* Kh = (_Float16*)(ws + ((size_t)48 << 20));
  _Float16* Vt = (_Float16*)(ws + ((size_t)52 << 20));
  _Float16* P0q = (_Float16*)d_out;
  _Float16* WreH = WqH;
  _Float16* qattn = (_Float16*)(ws);
  _Float16* lnH = (_Float16*)(ws + ((size_t)48 << 20));

  prepA<<<20480, 256, 0, stream>>>(emb, Wq, keys, values, embH, WqH, Kh, Vt);
  gemm_bt<1><<<dim3(32, 16), 256, 0, stream>>>(embH, WqH, nullptr, nullptr, P0q);
  prepB<<<10240, 256, 0, stream>>>(Wre, WreH, P0q, bq, qattn);
  attn_mfma<<<dim3(16, 64), 256, 0, stream>>>(qattn, Kh, Vt, out);
  ln_kernel<<<2048, 256, 0, stream>>>(out, ln_g, ln_b, lnH);
  gemm_bt<0><<<dim3(32, 16), 256, 0, stream>>>(lnH, WreH, bre, out, nullptr);
}